// Round 8
// baseline (460.205 us; speedup 1.0000x reference)
//
#include <hip/hip_runtime.h>
#include <math.h>

#define NN 16384
#define CAP 128    // per-query LDS candidate buffer (u64 keys)
#define WM 64      // shrink watermark; shrink inside push keeps cnt <= 127
#define KTOP 17    // keep top-17 (incl. self at dist~0), drop self at output
#define NSLAB 128  // z-slabs over [-4,4]
#define SH 0.0625f // slab width
#define SHI 16.0f  // 1/SH

typedef unsigned long long u64;

__device__ __forceinline__ int mbcnt64(u64 mask) {
  return __builtin_amdgcn_mbcnt_hi(
      (unsigned)(mask >> 32),
      __builtin_amdgcn_mbcnt_lo((unsigned)mask, 0));
}

// monotone float -> uint mapping (preserves total order incl. negatives)
__device__ __forceinline__ unsigned fmap(float d) {
  unsigned ub = __float_as_uint(d);
  return ub ^ ((unsigned)((int)ub >> 31) | 0x80000000u);
}

__device__ __forceinline__ float unfmap(unsigned ub) {
  unsigned fb = (ub & 0x80000000u) ? (ub ^ 0x80000000u) : ~ub;
  return __uint_as_float(fb);
}

// fp32 <-> bf16 (RNE, NaN-free data)
__device__ __forceinline__ unsigned short f2bf(float f) {
  unsigned u = __float_as_uint(f);
  return (unsigned short)((u + 0x7FFFu + ((u >> 16) & 1u)) >> 16);
}
__device__ __forceinline__ float bf2f(unsigned short h) {
  return __uint_as_float(((unsigned)h) << 16);
}

__device__ __forceinline__ u64 u64min(u64 a, u64 b) { return a < b ? a : b; }
__device__ __forceinline__ u64 u64max(u64 a, u64 b) { return a > b ? a : b; }

__device__ __forceinline__ int slabof(float v) {
  int c = (int)floorf((v + 4.0f) * SHI);
  return c < 0 ? 0 : (c > NSLAB - 1 ? NSLAB - 1 : c);
}

// bitonic sort of 64 u64 keys (1 reg/lane), ascending.
__device__ __forceinline__ void sort64(u64& r0, int lane) {
#pragma unroll
  for (int k = 2; k <= 64; k <<= 1) {
#pragma unroll
    for (int jj = k >> 1; jj >= 1; jj >>= 1) {
      const bool up = (lane & jj) == 0;
      const bool asc = (lane & k) == 0;
      u64 o = __shfl_xor(r0, jj);
      r0 = (up == asc) ? u64min(r0, o) : u64max(r0, o);
    }
  }
}

// full bitonic sort of 128 u64 keys as 2 regs/lane (virtual idx i0=lane,
// i1=lane+64), ascending.
__device__ __forceinline__ void sort128(u64& r0, u64& r1, int lane) {
#pragma unroll
  for (int k = 2; k <= 128; k <<= 1) {
    if (k == 128) {  // jj = 64 stage: partner is the other reg, same lane
      u64 lo = u64min(r0, r1);
      r1 = u64max(r0, r1);
      r0 = lo;
    }
#pragma unroll
    for (int jj = (k == 128 ? 32 : (k >> 1)); jj >= 1; jj >>= 1) {
      const bool up = (lane & jj) == 0;
      const bool asc0 = (lane & k) == 0;
      const bool asc1 = ((lane | 64) & k) == 0;
      u64 o0 = __shfl_xor(r0, jj);
      u64 o1 = __shfl_xor(r1, jj);
      r0 = (up == asc0) ? u64min(r0, o0) : u64max(r0, o0);
      r1 = (up == asc1) ? u64min(r1, o1) : u64max(r1, o1);
    }
  }
}

// r19 shrink: bitonic-sort the buffer, keep EXACTLY the 17 smallest u64 keys
// (final answer is the 17 smallest (key,idx) -- keeping exactly 17 is exact;
// future candidates with d <= d17 still pass the L >= cq filter). Replaces
// the 32-iteration serial-ballot radix select (~2000cy) with ~28 shfl stages
// (~700cy, no scalar round-trips). Requires cnt >= KTOP, cnt <= 128.
__device__ __forceinline__ void sort_shrink(u64* buf, int& cnt, float& cq,
                                            int lane) {
  u64 r0 = (lane < cnt) ? buf[lane] : ~0ull;
  u64 r1 = (lane + 64 < cnt) ? buf[lane + 64] : ~0ull;
  sort128(r0, r1, lane);
  const u64 k17 = __shfl(r0, KTOP - 1);  // 17th smallest (virtual idx 16)
  cq = -unfmap((unsigned)(k17 >> 32));   // keep L >= cq  <=>  d <= d17
  if (lane < KTOP) buf[lane] = r0;
  cnt = KTOP;
}

// ---------------- build: 128 z-slab counting sort ----------------
__global__ __launch_bounds__(256) void pack_slabs(const float* __restrict__ x,
                                                  float4* __restrict__ tmp4,
                                                  int* __restrict__ sid,
                                                  unsigned* __restrict__ hist) {
  const int i = blockIdx.x * 256 + threadIdx.x;
  const float a = x[i * 64 + 0];
  const float b = x[i * 64 + 1];
  const float c = x[i * 64 + 2];
  tmp4[i] = make_float4(a, b, c, -0.5f * (a * a + b * b + c * c));
  const int s = slabof(c);
  sid[i] = s;
  atomicAdd(&hist[s], 1u);
}

__global__ __launch_bounds__(128) void prefix_slabs(
    const unsigned* __restrict__ hist, unsigned* __restrict__ slabstart,
    unsigned* __restrict__ slabfill) {
  __shared__ unsigned ls[NSLAB];
  const int t = threadIdx.x;
  const unsigned h = hist[t];
  ls[t] = h;
  __syncthreads();
  for (int off = 1; off < NSLAB; off <<= 1) {
    const unsigned v = (t >= off) ? ls[t - off] : 0u;
    __syncthreads();
    ls[t] += v;
    __syncthreads();
  }
  const unsigned ex = ls[t] - h;  // exclusive
  slabstart[t] = ex;
  slabfill[t] = ex;
  if (t == NSLAB - 1) slabstart[NSLAB] = ls[t];  // = NN
}

__global__ __launch_bounds__(256) void scatter_slabs(
    const float4* __restrict__ tmp4, const int* __restrict__ sid,
    unsigned* __restrict__ slabfill, float4* __restrict__ sorted4,
    int* __restrict__ sidx) {
  const int i = blockIdx.x * 256 + threadIdx.x;
  const unsigned pos = atomicAdd(&slabfill[sid[i]], 1u);
  sorted4[pos] = tmp4[i];
  sidx[pos] = i;
}

// ---------------- kNN via z-slab window, prefill-seeded (r19) ---------------
// r18 lesson: remap + phase-split both regressed (reverted). r17/r18 PMC:
// time is serial-chain latency (convergence pushes + 32-step radix shrinks),
// not VALU. r19: (a) PREFILL the 64 index-adjacent points (z-nearest by
// sort) unconditionally + one shrink -> cq ~= true d17 BEFORE any window
// scan; the window scan then runs at ~1% pass rate (fast path only) and the
// first window, computed from the prefill upper bound, is already exact ->
// extension loop terminates in one check. (b) sort128-based shrink replaces
// the serial-ballot radix select. Skip-test excludes prefill range from all
// scans (no double-count). Exactness: keys fmap(-L)<<32|origIdx; keeping the
// 17 smallest keys at every shrink is exact w.r.t. the final 17-smallest-key
// output; self dropped at output; reference tie order preserved.
__global__ __launch_bounds__(256) void knn_z(
    const float4* __restrict__ sorted4, const int* __restrict__ sidx,
    const unsigned* __restrict__ slabstart, int* __restrict__ src) {
  __shared__ u64 bufs_[4][2][CAP];  // 8 KB
  const int lane = threadIdx.x & 63;
  const int wid = threadIdx.x >> 6;
  u64* buf0 = bufs_[wid][0];
  u64* buf1 = bufs_[wid][1];
  const int qpos = blockIdx.x * 8 + wid * 2;
  const float4 m0 = sorted4[qpos];
  const float4 m1 = sorted4[qpos + 1];
  const float qx0 = m0.x, qy0 = m0.y, qz0 = m0.z, q20 = -2.0f * m0.w;
  const float qx1 = m1.x, qy1 = m1.y, qz1 = m1.z, q21 = -2.0f * m1.w;
  float cq0, cq1;
  int cnt0, cnt1;

  // prefill: 64 index-adjacent points, unconditional push, one shrink each
  int pf_s = qpos - 31;
  if (pf_s < 0) pf_s = 0;
  int pf_e = pf_s + 64;
  if (pf_e > NN) {
    pf_e = NN;
    pf_s = pf_e - 64;
  }
  {
    const int j = pf_s + lane;
    const float4 p = sorted4[j];
    const float L0 = fmaf(qx0, p.x, fmaf(qy0, p.y, fmaf(qz0, p.z, p.w)));
    const float L1 = fmaf(qx1, p.x, fmaf(qy1, p.y, fmaf(qz1, p.z, p.w)));
    const unsigned oi = (unsigned)sidx[j];
    buf0[lane] = ((u64)fmap(-L0) << 32) | oi;
    buf1[lane] = ((u64)fmap(-L1) << 32) | oi;
    cnt0 = 64;
    cnt1 = 64;
    sort_shrink(buf0, cnt0, cq0, lane);
    sort_shrink(buf1, cnt1, cq1, lane);
  }

  auto scan_range = [&](int s, int e) {
    if (s >= e) return;
    int o = s;
    float4 p = sorted4[(s + lane) < e ? (s + lane) : s];
    while (o < e) {
      const int on = o + 64;
      float4 pn;
      if (on < e) {  // wave-uniform prefetch of next chunk
        const int jn = on + lane;
        pn = sorted4[jn < e ? jn : s];
      }
      const int j = o + lane;
      const bool in = (j < e) && (j < pf_s || j >= pf_e);  // skip prefill
      const float L0 = fmaf(qx0, p.x, fmaf(qy0, p.y, fmaf(qz0, p.z, p.w)));
      const float L1 = fmaf(qx1, p.x, fmaf(qy1, p.y, fmaf(qz1, p.z, p.w)));
      const bool p0 = in && (L0 >= cq0);
      const bool p1 = in && (L1 >= cq1);
      const u64 mk0 = __ballot(p0);
      const u64 mk1 = __ballot(p1);
      if (mk0 | mk1) {
        if (mk0) {  // wave-uniform
          if (p0)
            buf0[cnt0 + mbcnt64(mk0)] =
                ((u64)fmap(-L0) << 32) | (unsigned)sidx[j];
          cnt0 += __popcll(mk0);
          if (cnt0 >= WM) sort_shrink(buf0, cnt0, cq0, lane);
        }
        if (mk1) {
          if (p1)
            buf1[cnt1 + mbcnt64(mk1)] =
                ((u64)fmap(-L1) << 32) | (unsigned)sidx[j];
          cnt1 += __popcll(mk1);
          if (cnt1 >= WM) sort_shrink(buf1, cnt1, cq1, lane);
        }
      }
      o = on;
      p = pn;
    }
  };

  // window from prefill-converged cq (upper bound on d17 -> conservative)
  const float zmin = fminf(qz0, qz1), zmax = fmaxf(qz0, qz1);
  const float di0 = fmaxf(fmaf(-2.0f, cq0, q20), 0.0f);
  const float di1 = fmaxf(fmaf(-2.0f, cq1, q21), 0.0f);
  const float rn0 = sqrtf(fmaxf(di0, di1) * 1.00002f + 1e-4f);
  int slo = (int)floorf((zmin - rn0 + 4.0f) * SHI);
  int shi = (int)floorf((zmax + rn0 + 4.0f) * SHI);
  if (slo < 0) slo = 0;
  if (shi > NSLAB - 1) shi = NSLAB - 1;
  scan_range((int)slabstart[slo], (int)slabstart[shi + 1]);

  // safety extension loop (first window is from an upper bound -> normally
  // terminates in one pass with no extension)
  while (true) {
    if (cnt0 > KTOP) sort_shrink(buf0, cnt0, cq0, lane);
    if (cnt1 > KTOP) sort_shrink(buf1, cnt1, cq1, lane);
    const float d0 = fmaxf(fmaf(-2.0f, cq0, q20), 0.0f);
    const float d1 = fmaxf(fmaf(-2.0f, cq1, q21), 0.0f);
    const float rn = sqrtf(fmaxf(d0, d1) * 1.00002f + 1e-4f);
    int rlo = (int)floorf((zmin - rn + 4.0f) * SHI);
    int rhi = (int)floorf((zmax + rn + 4.0f) * SHI);
    if (rlo < 0) rlo = 0;
    if (rhi > NSLAB - 1) rhi = NSLAB - 1;
    if (rlo > slo) rlo = slo;  // window never shrinks
    if (rhi < shi) rhi = shi;
    bool ext = false;
    if (rlo < slo) {
      scan_range((int)slabstart[rlo], (int)slabstart[slo]);
      slo = rlo;
      ext = true;
    }
    if (rhi > shi) {
      scan_range((int)slabstart[shi + 1], (int)slabstart[rhi + 1]);
      shi = rhi;
      ext = true;
    }
    if (!ext) break;
  }

#pragma unroll 1
  for (int q = 0; q < 2; ++q) {
    u64* buf = q == 0 ? buf0 : buf1;
    int cnt = q == 0 ? cnt0 : cnt1;
    const int qorig = sidx[qpos + q];
    u64 r0 = (lane < cnt) ? buf[lane] : ~0ull;
    sort64(r0, lane);
    const int idx = (int)(r0 & 0xFFFFFFFFull);
    const u64 selfm = __ballot((lane < KTOP) && (idx == qorig));
    const int sp = selfm ? (__ffsll((long long)selfm) - 1) : 99;
    const int outrank = lane - (lane > sp ? 1 : 0);
    if (lane < KTOP && lane != sp && outrank < 16)
      src[qorig * 16 + outrank] = idx;
  }
}

// ---------------- fused q|k|v|s GEMM: [N,KD] x 4x[KD,128] ----------
// q,s -> fp32 qs[node][256] (q: 0..127, s: 128..255)
// k,v -> bf16 kvh[node][256] (k: 0..127, v: 128..255) -- halves attn gathers
template <int KD>
__global__ __launch_bounds__(256) void gemm_qkvs(
    const float* __restrict__ X, const float* __restrict__ W0,
    const float* __restrict__ W1, const float* __restrict__ W2,
    const float* __restrict__ W3, const float* __restrict__ B0,
    const float* __restrict__ B1, const float* __restrict__ B2,
    const float* __restrict__ B3, float* __restrict__ qs,
    unsigned short* __restrict__ kvh) {
  __shared__ float As[64][68];  // [k][row], padded k-stride 68
  __shared__ float Bs[64][64];  // [k][col]
  const int brow = blockIdx.x * 64;
  const int by = blockIdx.y;          // 0..7 -> (matrix, half)
  const int wi = by >> 1;
  const float* W = wi == 0 ? W0 : wi == 1 ? W1 : wi == 2 ? W2 : W3;
  const float* bias = wi == 0 ? B0 : wi == 1 ? B1 : wi == 2 ? B2 : B3;
  const int cbase = (by & 1) * 64;
  const int tx = threadIdx.x & 15;   // col group (4 cols)
  const int ty = threadIdx.x >> 4;   // row group (4 rows)

  float acc[4][4] = {};
  for (int k0 = 0; k0 < KD; k0 += 64) {
    __syncthreads();
#pragma unroll
    for (int i = 0; i < 4; ++i) {  // stage A transposed: 64 rows x 64 k
      const int flat = threadIdx.x * 4 + i * 1024;
      const int r = flat >> 6, kk = flat & 63;
      const float4 v = *(const float4*)&X[(brow + r) * KD + k0 + kk];
      As[kk + 0][r] = v.x;
      As[kk + 1][r] = v.y;
      As[kk + 2][r] = v.z;
      As[kk + 3][r] = v.w;
    }
#pragma unroll
    for (int i = 0; i < 4; ++i) {  // stage B: 64 k x 64 cols
      const int flat = threadIdx.x * 4 + i * 1024;
      const int kk = flat >> 6, c = flat & 63;
      *(float4*)&Bs[kk][c] = *(const float4*)&W[(k0 + kk) * 128 + cbase + c];
    }
    __syncthreads();
#pragma unroll 8
    for (int k = 0; k < 64; ++k) {
      const float4 a = *(const float4*)&As[k][ty * 4];
      const float4 b = *(const float4*)&Bs[k][tx * 4];
      const float av[4] = {a.x, a.y, a.z, a.w};
      const float bv[4] = {b.x, b.y, b.z, b.w};
#pragma unroll
      for (int i = 0; i < 4; ++i)
#pragma unroll
        for (int jj = 0; jj < 4; ++jj)
          acc[i][jj] = fmaf(av[i], bv[jj], acc[i][jj]);
    }
  }
  const float4 bi = *(const float4*)&bias[cbase + tx * 4];
  const int col = cbase + tx * 4;
#pragma unroll
  for (int i = 0; i < 4; ++i) {
    const int row = brow + ty * 4 + i;
    float4 o;
    o.x = acc[i][0] + bi.x;
    o.y = acc[i][1] + bi.y;
    o.z = acc[i][2] + bi.z;
    o.w = acc[i][3] + bi.w;
    if (wi == 0) {
      *(float4*)&qs[row * 256 + col] = o;
    } else if (wi == 3) {
      *(float4*)&qs[row * 256 + 128 + col] = o;
    } else {
      ushort4 h;
      h.x = f2bf(o.x);
      h.y = f2bf(o.y);
      h.z = f2bf(o.z);
      h.w = f2bf(o.w);
      *(ushort4*)&kvh[row * 256 + (wi == 1 ? col : 128 + col)] = h;
    }
  }
}

// ---------------- attention, c=128: 32-lane group per node ----
__global__ __launch_bounds__(256) void attn_c128(
    const float* __restrict__ qs, const unsigned short* __restrict__ kvh,
    const int* __restrict__ src, const float* __restrict__ res,
    float* __restrict__ hout, int do_res) {
  const int g = threadIdx.x >> 5;  // 8 groups of 32 lanes per block
  const int node = blockIdx.x * 8 + g;
  const int c = threadIdx.x & 31;
  const float4 q4 = ((const float4*)(qs + node * 256))[c];

  int nb[16];
#pragma unroll
  for (int r = 0; r < 16; ++r) nb[r] = src[node * 16 + r];

  float p[16];
#pragma unroll
  for (int r = 0; r < 16; ++r) {
    const ushort4 k4 = ((const ushort4*)(kvh + nb[r] * 256))[c];
    p[r] = q4.x * bf2f(k4.x) + q4.y * bf2f(k4.y) + q4.z * bf2f(k4.z) +
           q4.w * bf2f(k4.w);
  }
#pragma unroll
  for (int o = 16; o; o >>= 1) {  // group-local (xor offsets < 32)
#pragma unroll
    for (int r = 0; r < 16; ++r) p[r] += __shfl_xor(p[r], o);
  }

  float m = p[0];
#pragma unroll
  for (int r = 1; r < 16; ++r) m = fmaxf(m, p[r]);
  float w[16];
  float den = 0.0f;
#pragma unroll
  for (int r = 0; r < 16; ++r) {
    w[r] = __expf((p[r] - m) * 0.088388347648318447f);  // 1/sqrt(128)
    den += w[r];
  }
  const float inv = 1.0f / den;
  float o0 = 0.0f, o1 = 0.0f, o2 = 0.0f, o3 = 0.0f;
#pragma unroll
  for (int r = 0; r < 16; ++r) {
    const ushort4 v4 = ((const ushort4*)(kvh + nb[r] * 256 + 128))[c];
    const float ww = w[r] * inv;
    o0 = fmaf(ww, bf2f(v4.x), o0);
    o1 = fmaf(ww, bf2f(v4.y), o1);
    o2 = fmaf(ww, bf2f(v4.z), o2);
    o3 = fmaf(ww, bf2f(v4.w), o3);
  }
  const float4 s4 = ((const float4*)(qs + node * 256 + 128))[c];
  float r0 = o0 + s4.x, r1 = o1 + s4.y, r2 = o2 + s4.z, r3 = o3 + s4.w;
  if (do_res) {
    const float4 h4 = ((const float4*)(res + node * 128))[c];
    r0 += h4.x;
    r1 += h4.y;
    r2 += h4.z;
    r3 += h4.w;
  }
  ((float4*)(hout + node * 128))[c] =
      make_float4(tanhf(r0), tanhf(r1), tanhf(r2), tanhf(r3));
}

// ---------------- layer 3 GEMM: [N,128] x 4x[128,3] -> [N,12] ----------------
__global__ __launch_bounds__(256) void gemm_qkvs3(
    const float* __restrict__ H, const float* __restrict__ W0,
    const float* __restrict__ W1, const float* __restrict__ W2,
    const float* __restrict__ W3, const float* __restrict__ B0,
    const float* __restrict__ B1, const float* __restrict__ B2,
    const float* __restrict__ B3, float* __restrict__ out) {
  __shared__ float hs[64][132];
  __shared__ float wsh[128 * 12];
  __shared__ float bsh[12];
  const int brow = blockIdx.x * 64;
  if (threadIdx.x < 12) {
    const int mi = threadIdx.x / 3, c = threadIdx.x % 3;
    const float* Bsel = mi == 0 ? B0 : mi == 1 ? B1 : mi == 2 ? B2 : B3;
    bsh[threadIdx.x] = Bsel[c];
  }
  for (int t = threadIdx.x; t < 1536; t += 256) {
    const int k = t / 12, cc = t % 12;
    const int mi = cc / 3, c = cc % 3;
    const float* Wsel = mi == 0 ? W0 : mi == 1 ? W1 : mi == 2 ? W2 : W3;
    wsh[t] = Wsel[k * 3 + c];
  }
#pragma unroll
  for (int i = 0; i < 8; ++i) {
    const int flat = threadIdx.x * 4 + i * 1024;
    const int r = flat >> 7, kk = flat & 127;
    *(float4*)&hs[r][kk] = *(const float4*)&H[(brow + r) * 128 + kk];
  }
  __syncthreads();
  const int r = threadIdx.x >> 2;
  const int part = threadIdx.x & 3;
  float a0 = 0.0f, a1 = 0.0f, a2 = 0.0f;
#pragma unroll 4
  for (int k = 0; k < 128; ++k) {
    const float h = hs[r][k];
    a0 = fmaf(h, wsh[k * 12 + part * 3 + 0], a0);
    a1 = fmaf(h, wsh[k * 12 + part * 3 + 1], a1);
    a2 = fmaf(h, wsh[k * 12 + part * 3 + 2], a2);
  }
  const int row = brow + r;
  out[row * 12 + part * 3 + 0] = a0 + bsh[part * 3 + 0];
  out[row * 12 + part * 3 + 1] = a1 + bsh[part * 3 + 1];
  out[row * 12 + part * 3 + 2] = a2 + bsh[part * 3 + 2];
}

// ---------------- attention, c=3: 16 lanes per node ----------------
__global__ __launch_bounds__(256) void attn_c3(const float* __restrict__ q3,
                                               const int* __restrict__ src,
                                               float* __restrict__ out) {
  const int gid = blockIdx.x * 256 + threadIdx.x;
  const int node = gid >> 4, r = gid & 15;
  const int j = src[node * 16 + r];
  const float* qn = q3 + node * 12;
  const float* kj = q3 + j * 12 + 3;
  float alpha = (qn[0] * kj[0] + qn[1] * kj[1] + qn[2] * kj[2]) *
                0.57735026918962576f;  // 1/sqrt(3)
  float m = alpha;
#pragma unroll
  for (int o = 8; o; o >>= 1) m = fmaxf(m, __shfl_xor(m, o, 16));
  const float e = __expf(alpha - m);
  float den = e;
#pragma unroll
  for (int o = 8; o; o >>= 1) den += __shfl_xor(den, o, 16);
  const float wgt = e / den;
  const float* vj = q3 + j * 12 + 6;
  float o0 = wgt * vj[0], o1 = wgt * vj[1], o2 = wgt * vj[2];
#pragma unroll
  for (int o = 8; o; o >>= 1) {
    o0 += __shfl_xor(o0, o, 16);
    o1 += __shfl_xor(o1, o, 16);
    o2 += __shfl_xor(o2, o, 16);
  }
  if (r == 0) {
    const float* sn = q3 + node * 12 + 9;
    out[node * 3 + 0] = o0 + sn[0];
    out[node * 3 + 1] = o1 + sn[1];
    out[node * 3 + 2] = o2 + sn[2];
  }
}

extern "C" void kernel_launch(void* const* d_in, const int* in_sizes, int n_in,
                              void* d_out, int out_size, void* d_ws,
                              size_t ws_size, hipStream_t stream) {
  const float* x = (const float*)d_in[1];
  const float* Wq1 = (const float*)d_in[2];
  const float* bq1 = (const float*)d_in[3];
  const float* Wk1 = (const float*)d_in[4];
  const float* bk1 = (const float*)d_in[5];
  const float* Wv1 = (const float*)d_in[6];
  const float* bv1 = (const float*)d_in[7];
  const float* Ws1 = (const float*)d_in[8];
  const float* bs1 = (const float*)d_in[9];
  const float* Wq2 = (const float*)d_in[10];
  const float* bq2 = (const float*)d_in[11];
  const float* Wk2 = (const float*)d_in[12];
  const float* bk2 = (const float*)d_in[13];
  const float* Wv2 = (const float*)d_in[14];
  const float* bv2 = (const float*)d_in[15];
  const float* Ws2 = (const float*)d_in[16];
  const float* bs2 = (const float*)d_in[17];
  const float* Wq3 = (const float*)d_in[18];
  const float* bq3 = (const float*)d_in[19];
  const float* Wk3 = (const float*)d_in[20];
  const float* bk3 = (const float*)d_in[21];
  const float* Wv3 = (const float*)d_in[22];
  const float* bv3 = (const float*)d_in[23];
  const float* Ws3 = (const float*)d_in[24];
  const float* bs3 = (const float*)d_in[25];

  const size_t MB = 1024 * 1024;
  const size_t KB = 1024;
  char* ws = (char*)d_ws;
  // knn build temporaries live in the qs region [0,16MB): dead until gemm1,
  // which runs strictly after knn_z on the same stream.
  float4* tmp4 = (float4*)(ws);                           // 256 KB
  float4* sorted4 = (float4*)(ws + 256 * KB);             // 256 KB
  int* sid = (int*)(ws + 512 * KB);                       // 64 KB
  int* sidx = (int*)(ws + 576 * KB);                      // 64 KB
  unsigned* hist = (unsigned*)(ws + 640 * KB);            // 512 B
  unsigned* slabstart = (unsigned*)(ws + 644 * KB);       // 516 B
  unsigned* slabfill = (unsigned*)(ws + 648 * KB);        // 512 B

  float* qs = (float*)(ws);                               // 16 MB (q|s fp32)
  unsigned short* kvh = (unsigned short*)(ws + 16 * MB);  // 8 MB (k|v bf16)
  float* h1 = (float*)(ws + 24 * MB);                     // 8 MB
  float* h2 = (float*)(ws + 32 * MB);                     // 8 MB
  int* src = (int*)(ws + 40 * MB);                        // 1 MB
  float* q3 = (float*)(ws + 42 * MB);                     // 768 KB
  float* out = (float*)d_out;

  hipMemsetAsync(hist, 0, NSLAB * sizeof(unsigned), stream);
  pack_slabs<<<NN / 256, 256, 0, stream>>>(x, tmp4, sid, hist);
  prefix_slabs<<<1, NSLAB, 0, stream>>>(hist, slabstart, slabfill);
  scatter_slabs<<<NN / 256, 256, 0, stream>>>(tmp4, sid, slabfill, sorted4,
                                              sidx);
  knn_z<<<NN / 8, 256, 0, stream>>>(sorted4, sidx, slabstart, src);
  gemm_qkvs<64><<<dim3(NN / 64, 8), 256, 0, stream>>>(
      x, Wq1, Wk1, Wv1, Ws1, bq1, bk1, bv1, bs1, qs, kvh);
  attn_c128<<<NN / 8, 256, 0, stream>>>(qs, kvh, src, nullptr, h1, 0);
  gemm_qkvs<128><<<dim3(NN / 64, 8), 256, 0, stream>>>(
      h1, Wq2, Wk2, Wv2, Ws2, bq2, bk2, bv2, bs2, qs, kvh);
  attn_c128<<<NN / 8, 256, 0, stream>>>(qs, kvh, src, h1, h2, 1);
  gemm_qkvs3<<<NN / 64, 256, 0, stream>>>(h2, Wq3, Wk3, Wv3, Ws3, bq3, bk3,
                                          bv3, bs3, q3);
  attn_c3<<<NN * 16 / 256, 256, 0, stream>>>(q3, src, out);
}

// Round 9
// 342.160 us; speedup vs baseline: 1.3450x; 1.3450x over previous
//
#include <hip/hip_runtime.h>
#include <math.h>

#define NN 16384
#define QPW 2      // queries per wave (r12: QPW=4 regressed)
#define CAP 128    // per-query LDS candidate buffer (u64 keys)
#define WM 64      // shrink watermark; shrink inside push keeps cnt <= 127
#define KTOP 17    // keep top-17 (incl. self at dist~0), drop self at output
#define NSLAB 128  // z-slabs over [-4,4] (used ONLY to build the attn sort)
#define SHI 16.0f  // 1/slab width

typedef unsigned long long u64;

__device__ __forceinline__ int mbcnt64(u64 mask) {
  return __builtin_amdgcn_mbcnt_hi(
      (unsigned)(mask >> 32),
      __builtin_amdgcn_mbcnt_lo((unsigned)mask, 0));
}

// monotone float -> uint mapping (preserves total order incl. negatives)
__device__ __forceinline__ unsigned fmap(float d) {
  unsigned ub = __float_as_uint(d);
  return ub ^ ((unsigned)((int)ub >> 31) | 0x80000000u);
}

__device__ __forceinline__ float unfmap(unsigned ub) {
  unsigned fb = (ub & 0x80000000u) ? (ub ^ 0x80000000u) : ~ub;
  return __uint_as_float(fb);
}

// fp32 <-> bf16 (RNE, NaN-free data)
__device__ __forceinline__ unsigned short f2bf(float f) {
  unsigned u = __float_as_uint(f);
  return (unsigned short)((u + 0x7FFFu + ((u >> 16) & 1u)) >> 16);
}
__device__ __forceinline__ float bf2f(unsigned short h) {
  return __uint_as_float(((unsigned)h) << 16);
}

__device__ __forceinline__ u64 u64min(u64 a, u64 b) { return a < b ? a : b; }
__device__ __forceinline__ u64 u64max(u64 a, u64 b) { return a > b ? a : b; }

__device__ __forceinline__ int slabof(float v) {
  int c = (int)floorf((v + 4.0f) * SHI);
  return c < 0 ? 0 : (c > NSLAB - 1 ? NSLAB - 1 : c);
}

// full bitonic sort of 128 u64 keys held as 2 regs/lane, ascending.
__device__ __forceinline__ void sort128(u64& r0, u64& r1, int lane) {
#pragma unroll
  for (int k = 2; k <= 128; k <<= 1) {
    if (k == 128) {  // jj = 64 stage: partner is the other reg, same lane
      u64 lo = u64min(r0, r1);
      r1 = u64max(r0, r1);
      r0 = lo;
    }
#pragma unroll
    for (int jj = (k == 128 ? 32 : (k >> 1)); jj >= 1; jj >>= 1) {
      const bool up = (lane & jj) == 0;
      const bool asc0 = (lane & k) == 0;
      const bool asc1 = ((lane | 64) & k) == 0;
      u64 o0 = __shfl_xor(r0, jj);
      u64 o1 = __shfl_xor(r1, jj);
      r0 = (up == asc0) ? u64min(r0, o0) : u64max(r0, o0);
      r1 = (up == asc1) ? u64min(r1, o1) : u64max(r1, o1);
    }
  }
}

// radix-select shrink (r14-proven): p = KTOP-th smallest mapped key among
// buf[0..cnt), keep all entries with key <= p (ties kept -> exactness),
// compact to front. Key domain fmap(-L); cq = L_kth: keep L >= cq.
__device__ __forceinline__ void radix_shrink(u64* buf, int& cnt, float& cq,
                                             int lane) {
  const u64 k0 = (lane < cnt) ? buf[lane] : ~0ull;
  const u64 k1 = (lane + 64 < cnt) ? buf[lane + 64] : ~0ull;
  const unsigned d0 = (unsigned)(k0 >> 32);
  const unsigned d1 = (unsigned)(k1 >> 32);
  unsigned p = 0u;
#pragma unroll
  for (int b = 31; b >= 0; --b) {
    const unsigned c = p | (1u << b);
    const u64 b0 = __ballot(d0 < c);
    const u64 b1 = __ballot(d1 < c);
    const int n = __popcll(b0) + __popcll(b1);
    if (n < KTOP) p = c;  // invariant: count(key < p) < KTOP
  }
  const bool v0 = d0 <= p;
  const bool v1 = d1 <= p;
  const u64 m0 = __ballot(v0);
  const u64 m1 = __ballot(v1);
  const int base = __popcll(m0);
  if (v0) buf[mbcnt64(m0)] = k0;
  if (v1) buf[base + mbcnt64(m1)] = k1;
  cnt = base + __popcll(m1);
  cq = -unfmap(p);
}

// ---------------- build: coords (orig order) + z-sort permutation ----------
// coo[i] = (x,y,z,-|p|^2/2) for the knn hot loop (r14 algebra).
// sid/hist feed a 128-slab counting sort -> sidx (pos->orig), rank (orig->pos)
// used ONLY to lay out the attn/gemm chain in z-local row order (r20).
__global__ __launch_bounds__(256) void pack_all(const float* __restrict__ x,
                                                float4* __restrict__ coo,
                                                int* __restrict__ sid,
                                                unsigned* __restrict__ hist) {
  const int i = blockIdx.x * 256 + threadIdx.x;
  const float a = x[i * 64 + 0];
  const float b = x[i * 64 + 1];
  const float c = x[i * 64 + 2];
  coo[i] = make_float4(a, b, c, -0.5f * (a * a + b * b + c * c));
  const int s = slabof(c);
  sid[i] = s;
  atomicAdd(&hist[s], 1u);
}

__global__ __launch_bounds__(128) void prefix_slabs(
    const unsigned* __restrict__ hist, unsigned* __restrict__ slabfill) {
  __shared__ unsigned ls[NSLAB];
  const int t = threadIdx.x;
  const unsigned h = hist[t];
  ls[t] = h;
  __syncthreads();
  for (int off = 1; off < NSLAB; off <<= 1) {
    const unsigned v = (t >= off) ? ls[t - off] : 0u;
    __syncthreads();
    ls[t] += v;
    __syncthreads();
  }
  slabfill[t] = ls[t] - h;  // exclusive prefix
}

__global__ __launch_bounds__(256) void rank_scatter(
    const int* __restrict__ sid, unsigned* __restrict__ slabfill,
    int* __restrict__ sidx, int* __restrict__ rank) {
  const int i = blockIdx.x * 256 + threadIdx.x;
  const int pos = (int)atomicAdd(&slabfill[sid[i]], 1u);
  sidx[pos] = i;
  rank[i] = pos;
}

// ---------------- kNN: r14-proven brute force (REVERTED after r15-r19 all
// regressed: spatial pruning feeds all-plausible candidates -> push/shrink
// chains dominate; random-order scan self-converges cheaply). Wave handles
// 2 nodes over the FULL database, 64 cand/step, test L >= cq (3 FMA + cmp),
// 4 NAMED prefetch slots. Only r20 change: outputs are written into the
// z-sorted index space (srcs[rank[q]*16+r] = rank[idx]) for attn locality;
// keys keep ORIG indices so tie order and self-drop are untouched. ----------
__global__ __launch_bounds__(256) void knn_kernel(const float4* __restrict__ coo,
                                                  const int* __restrict__ rank,
                                                  int* __restrict__ srcs) {
  __shared__ u64 bufs[4][QPW][CAP];  // 8 KB
  const int lane = threadIdx.x & 63;
  const int wid = threadIdx.x >> 6;
  const int node0 = blockIdx.x * (4 * QPW) + wid * QPW;

  float qx[QPW], qy[QPW], qz[QPW], cq[QPW];
  int cnt[QPW];
#pragma unroll
  for (int q = 0; q < QPW; ++q) {
    const float4 me = coo[node0 + q];
    qx[q] = me.x;
    qy[q] = me.y;
    qz[q] = me.z;
    cnt[q] = 0;
  }

  // pre-fill: candidates j = 0..127 direct into buffer, shrink
  {
    const float4 pa = coo[lane];
    const float4 pb = coo[64 + lane];
#pragma unroll
    for (int q = 0; q < QPW; ++q) {
      const float L0 = fmaf(qx[q], pa.x,
                        fmaf(qy[q], pa.y, fmaf(qz[q], pa.z, pa.w)));
      const float L1 = fmaf(qx[q], pb.x,
                        fmaf(qy[q], pb.y, fmaf(qz[q], pb.z, pb.w)));
      bufs[wid][q][lane] = ((u64)fmap(-L0) << 32) | (unsigned)lane;
      bufs[wid][q][64 + lane] = ((u64)fmap(-L1) << 32) | (unsigned)(64 + lane);
      cnt[q] = 128;
      radix_shrink(bufs[wid][q], cnt[q], cq[q], lane);
    }
  }

  // named prefetch slots: steps 2,3,4,5
  float4 s0 = coo[2 * 64 + lane];
  float4 s1 = coo[3 * 64 + lane];
  float4 s2 = coo[4 * 64 + lane];
  float4 s3 = coo[5 * 64 + lane];

  auto body = [&](const float4 cur, const int step) {
    const int j = step * 64 + lane;
    float L[QPW];
#pragma unroll
    for (int q = 0; q < QPW; ++q)
      L[q] = fmaf(qx[q], cur.x,
                  fmaf(qy[q], cur.y, fmaf(qz[q], cur.z, cur.w)));
    u64 mk[QPW];
#pragma unroll
    for (int q = 0; q < QPW; ++q) mk[q] = __ballot(L[q] >= cq[q]);
    if (mk[0] | mk[1]) {
#pragma unroll
      for (int q = 0; q < QPW; ++q) {
        if (mk[q]) {  // wave-uniform
          if (L[q] >= cq[q])
            bufs[wid][q][cnt[q] + mbcnt64(mk[q])] =
                ((u64)fmap(-L[q]) << 32) | (unsigned)j;
          cnt[q] += __popcll(mk[q]);
          if (cnt[q] >= WM) radix_shrink(bufs[wid][q], cnt[q], cq[q], lane);
        }
      }
    }
  };

  // steps 2..253 in 63 groups of 4; slots referenced by NAME only.
  // Over-reads at g=62 (steps 256,257) stay inside the pad after coo.
#pragma unroll 1
  for (int g = 0; g < 63; ++g) {
    const int base = 2 + g * 4;
    body(s0, base + 0);
    s0 = coo[(base + 4) * 64 + lane];
    body(s1, base + 1);
    s1 = coo[(base + 5) * 64 + lane];
    body(s2, base + 2);
    s2 = coo[(base + 6) * 64 + lane];
    body(s3, base + 3);
    s3 = coo[(base + 7) * 64 + lane];
  }
  body(s0, 254);
  body(s1, 255);

#pragma unroll 1
  for (int q = 0; q < QPW; ++q) {
    // final: exact (key, idx)-sorted top-17 via one bitonic sort
    u64 r0 = (lane < cnt[q]) ? bufs[wid][q][lane] : ~0ull;
    u64 r1 = (lane + 64 < cnt[q]) ? bufs[wid][q][lane + 64] : ~0ull;
    sort128(r0, r1, lane);
    const int idx = (int)(r0 & 0xFFFFFFFFull);
    const u64 selfm = __ballot((lane < KTOP) && (idx == node0 + q));
    const int s = selfm ? (__ffsll((long long)selfm) - 1) : 99;
    const int outrank = lane - (lane > s ? 1 : 0);
    const int qsp = rank[node0 + q];  // query's sorted position
    if (lane < KTOP && lane != s && outrank < 16)
      srcs[qsp * 16 + outrank] = rank[idx];  // neighbor's sorted position
  }
}

// ---------------- fused q|k|v|s GEMM: [N,KD] x 4x[KD,128] ----------
// q,s -> fp32 qs[orow][256]; k,v -> bf16 kvh[orow][256]. r20: orow = rmap[row]
// (z-sorted position) for layer 1 so the attn gather is z-local; layer 2
// passes rmap=null (h1 already sorted).
template <int KD>
__global__ __launch_bounds__(256) void gemm_qkvs(
    const float* __restrict__ X, const float* __restrict__ W0,
    const float* __restrict__ W1, const float* __restrict__ W2,
    const float* __restrict__ W3, const float* __restrict__ B0,
    const float* __restrict__ B1, const float* __restrict__ B2,
    const float* __restrict__ B3, const int* __restrict__ rmap,
    float* __restrict__ qs, unsigned short* __restrict__ kvh) {
  __shared__ float As[64][68];  // [k][row], padded k-stride 68
  __shared__ float Bs[64][64];  // [k][col]
  const int brow = blockIdx.x * 64;
  const int by = blockIdx.y;          // 0..7 -> (matrix, half)
  const int wi = by >> 1;
  const float* W = wi == 0 ? W0 : wi == 1 ? W1 : wi == 2 ? W2 : W3;
  const float* bias = wi == 0 ? B0 : wi == 1 ? B1 : wi == 2 ? B2 : B3;
  const int cbase = (by & 1) * 64;
  const int tx = threadIdx.x & 15;   // col group (4 cols)
  const int ty = threadIdx.x >> 4;   // row group (4 rows)

  float acc[4][4] = {};
  for (int k0 = 0; k0 < KD; k0 += 64) {
    __syncthreads();
#pragma unroll
    for (int i = 0; i < 4; ++i) {  // stage A transposed: 64 rows x 64 k
      const int flat = threadIdx.x * 4 + i * 1024;
      const int r = flat >> 6, kk = flat & 63;
      const float4 v = *(const float4*)&X[(brow + r) * KD + k0 + kk];
      As[kk + 0][r] = v.x;
      As[kk + 1][r] = v.y;
      As[kk + 2][r] = v.z;
      As[kk + 3][r] = v.w;
    }
#pragma unroll
    for (int i = 0; i < 4; ++i) {  // stage B: 64 k x 64 cols
      const int flat = threadIdx.x * 4 + i * 1024;
      const int kk = flat >> 6, c = flat & 63;
      *(float4*)&Bs[kk][c] = *(const float4*)&W[(k0 + kk) * 128 + cbase + c];
    }
    __syncthreads();
#pragma unroll 8
    for (int k = 0; k < 64; ++k) {
      const float4 a = *(const float4*)&As[k][ty * 4];
      const float4 b = *(const float4*)&Bs[k][tx * 4];
      const float av[4] = {a.x, a.y, a.z, a.w};
      const float bv[4] = {b.x, b.y, b.z, b.w};
#pragma unroll
      for (int i = 0; i < 4; ++i)
#pragma unroll
        for (int jj = 0; jj < 4; ++jj)
          acc[i][jj] = fmaf(av[i], bv[jj], acc[i][jj]);
    }
  }
  const float4 bi = *(const float4*)&bias[cbase + tx * 4];
  const int col = cbase + tx * 4;
#pragma unroll
  for (int i = 0; i < 4; ++i) {
    const int row = brow + ty * 4 + i;
    const int orow = rmap ? rmap[row] : row;
    float4 o;
    o.x = acc[i][0] + bi.x;
    o.y = acc[i][1] + bi.y;
    o.z = acc[i][2] + bi.z;
    o.w = acc[i][3] + bi.w;
    if (wi == 0) {
      *(float4*)&qs[orow * 256 + col] = o;
    } else if (wi == 3) {
      *(float4*)&qs[orow * 256 + 128 + col] = o;
    } else {
      ushort4 h;
      h.x = f2bf(o.x);
      h.y = f2bf(o.y);
      h.z = f2bf(o.z);
      h.w = f2bf(o.w);
      *(ushort4*)&kvh[orow * 256 + (wi == 1 ? col : 128 + col)] = h;
    }
  }
}

// ---------------- attention, c=128: 32-lane group per node ----
// r20: node = z-sorted position; srcs holds sorted positions -> the 16-row
// K/V gathers land in a small z-local window (L1/L2-hot) instead of random
// rows of the 8 MB kvh table.
__global__ __launch_bounds__(256) void attn_c128(
    const float* __restrict__ qs, const unsigned short* __restrict__ kvh,
    const int* __restrict__ srcs, const float* __restrict__ res,
    float* __restrict__ hout, int do_res) {
  const int g = threadIdx.x >> 5;  // 8 groups of 32 lanes per block
  const int node = blockIdx.x * 8 + g;
  const int c = threadIdx.x & 31;
  const float4 q4 = ((const float4*)(qs + node * 256))[c];

  int nb[16];
#pragma unroll
  for (int r = 0; r < 16; ++r) nb[r] = srcs[node * 16 + r];

  float p[16];
#pragma unroll
  for (int r = 0; r < 16; ++r) {
    const ushort4 k4 = ((const ushort4*)(kvh + nb[r] * 256))[c];
    p[r] = q4.x * bf2f(k4.x) + q4.y * bf2f(k4.y) + q4.z * bf2f(k4.z) +
           q4.w * bf2f(k4.w);
  }
#pragma unroll
  for (int o = 16; o; o >>= 1) {  // group-local (xor offsets < 32)
#pragma unroll
    for (int r = 0; r < 16; ++r) p[r] += __shfl_xor(p[r], o);
  }

  float m = p[0];
#pragma unroll
  for (int r = 1; r < 16; ++r) m = fmaxf(m, p[r]);
  float w[16];
  float den = 0.0f;
#pragma unroll
  for (int r = 0; r < 16; ++r) {
    w[r] = __expf((p[r] - m) * 0.088388347648318447f);  // 1/sqrt(128)
    den += w[r];
  }
  const float inv = 1.0f / den;
  float o0 = 0.0f, o1 = 0.0f, o2 = 0.0f, o3 = 0.0f;
#pragma unroll
  for (int r = 0; r < 16; ++r) {
    const ushort4 v4 = ((const ushort4*)(kvh + nb[r] * 256 + 128))[c];
    const float ww = w[r] * inv;
    o0 = fmaf(ww, bf2f(v4.x), o0);
    o1 = fmaf(ww, bf2f(v4.y), o1);
    o2 = fmaf(ww, bf2f(v4.z), o2);
    o3 = fmaf(ww, bf2f(v4.w), o3);
  }
  const float4 s4 = ((const float4*)(qs + node * 256 + 128))[c];
  float r0 = o0 + s4.x, r1 = o1 + s4.y, r2 = o2 + s4.z, r3 = o3 + s4.w;
  if (do_res) {
    const float4 h4 = ((const float4*)(res + node * 128))[c];
    r0 += h4.x;
    r1 += h4.y;
    r2 += h4.z;
    r3 += h4.w;
  }
  ((float4*)(hout + node * 128))[c] =
      make_float4(tanhf(r0), tanhf(r1), tanhf(r2), tanhf(r3));
}

// ---------------- layer 3 GEMM: [N,128] x 4x[128,3] -> [N,12] ----------------
__global__ __launch_bounds__(256) void gemm_qkvs3(
    const float* __restrict__ H, const float* __restrict__ W0,
    const float* __restrict__ W1, const float* __restrict__ W2,
    const float* __restrict__ W3, const float* __restrict__ B0,
    const float* __restrict__ B1, const float* __restrict__ B2,
    const float* __restrict__ B3, float* __restrict__ out) {
  __shared__ float hs[64][132];
  __shared__ float wsh[128 * 12];
  __shared__ float bsh[12];
  const int brow = blockIdx.x * 64;
  if (threadIdx.x < 12) {
    const int mi = threadIdx.x / 3, c = threadIdx.x % 3;
    const float* Bsel = mi == 0 ? B0 : mi == 1 ? B1 : mi == 2 ? B2 : B3;
    bsh[threadIdx.x] = Bsel[c];
  }
  for (int t = threadIdx.x; t < 1536; t += 256) {
    const int k = t / 12, cc = t % 12;
    const int mi = cc / 3, c = cc % 3;
    const float* Wsel = mi == 0 ? W0 : mi == 1 ? W1 : mi == 2 ? W2 : W3;
    wsh[t] = Wsel[k * 3 + c];
  }
#pragma unroll
  for (int i = 0; i < 8; ++i) {
    const int flat = threadIdx.x * 4 + i * 1024;
    const int r = flat >> 7, kk = flat & 127;
    *(float4*)&hs[r][kk] = *(const float4*)&H[(brow + r) * 128 + kk];
  }
  __syncthreads();
  const int r = threadIdx.x >> 2;
  const int part = threadIdx.x & 3;
  float a0 = 0.0f, a1 = 0.0f, a2 = 0.0f;
#pragma unroll 4
  for (int k = 0; k < 128; ++k) {
    const float h = hs[r][k];
    a0 = fmaf(h, wsh[k * 12 + part * 3 + 0], a0);
    a1 = fmaf(h, wsh[k * 12 + part * 3 + 1], a1);
    a2 = fmaf(h, wsh[k * 12 + part * 3 + 2], a2);
  }
  const int row = brow + r;
  out[row * 12 + part * 3 + 0] = a0 + bsh[part * 3 + 0];
  out[row * 12 + part * 3 + 1] = a1 + bsh[part * 3 + 1];
  out[row * 12 + part * 3 + 2] = a2 + bsh[part * 3 + 2];
}

// ---------------- attention, c=3: 16 lanes per node ----------------
// r20: node = sorted position; final write scattered back to orig order.
__global__ __launch_bounds__(256) void attn_c3(const float* __restrict__ q3,
                                               const int* __restrict__ srcs,
                                               const int* __restrict__ sidx,
                                               float* __restrict__ out) {
  const int gid = blockIdx.x * 256 + threadIdx.x;
  const int node = gid >> 4, r = gid & 15;
  const int j = srcs[node * 16 + r];
  const float* qn = q3 + node * 12;
  const float* kj = q3 + j * 12 + 3;
  float alpha = (qn[0] * kj[0] + qn[1] * kj[1] + qn[2] * kj[2]) *
                0.57735026918962576f;  // 1/sqrt(3)
  float m = alpha;
#pragma unroll
  for (int o = 8; o; o >>= 1) m = fmaxf(m, __shfl_xor(m, o, 16));
  const float e = __expf(alpha - m);
  float den = e;
#pragma unroll
  for (int o = 8; o; o >>= 1) den += __shfl_xor(den, o, 16);
  const float wgt = e / den;
  const float* vj = q3 + j * 12 + 6;
  float o0 = wgt * vj[0], o1 = wgt * vj[1], o2 = wgt * vj[2];
#pragma unroll
  for (int o = 8; o; o >>= 1) {
    o0 += __shfl_xor(o0, o, 16);
    o1 += __shfl_xor(o1, o, 16);
    o2 += __shfl_xor(o2, o, 16);
  }
  if (r == 0) {
    const float* sn = q3 + node * 12 + 9;
    const int onode = sidx[node];  // un-permute at the very end
    out[onode * 3 + 0] = o0 + sn[0];
    out[onode * 3 + 1] = o1 + sn[1];
    out[onode * 3 + 2] = o2 + sn[2];
  }
}

extern "C" void kernel_launch(void* const* d_in, const int* in_sizes, int n_in,
                              void* d_out, int out_size, void* d_ws,
                              size_t ws_size, hipStream_t stream) {
  const float* x = (const float*)d_in[1];
  const float* Wq1 = (const float*)d_in[2];
  const float* bq1 = (const float*)d_in[3];
  const float* Wk1 = (const float*)d_in[4];
  const float* bk1 = (const float*)d_in[5];
  const float* Wv1 = (const float*)d_in[6];
  const float* bv1 = (const float*)d_in[7];
  const float* Ws1 = (const float*)d_in[8];
  const float* bs1 = (const float*)d_in[9];
  const float* Wq2 = (const float*)d_in[10];
  const float* bq2 = (const float*)d_in[11];
  const float* Wk2 = (const float*)d_in[12];
  const float* bk2 = (const float*)d_in[13];
  const float* Wv2 = (const float*)d_in[14];
  const float* bv2 = (const float*)d_in[15];
  const float* Ws2 = (const float*)d_in[16];
  const float* bs2 = (const float*)d_in[17];
  const float* Wq3 = (const float*)d_in[18];
  const float* bq3 = (const float*)d_in[19];
  const float* Wk3 = (const float*)d_in[20];
  const float* bk3 = (const float*)d_in[21];
  const float* Wv3 = (const float*)d_in[22];
  const float* bv3 = (const float*)d_in[23];
  const float* Ws3 = (const float*)d_in[24];
  const float* bs3 = (const float*)d_in[25];

  const size_t MB = 1024 * 1024;
  const size_t KB = 1024;
  char* ws = (char*)d_ws;
  float* qs = (float*)(ws);                               // 16 MB (q|s fp32)
  unsigned short* kvh = (unsigned short*)(ws + 16 * MB);  // 8 MB (k|v bf16)
  float* h1 = (float*)(ws + 24 * MB);                     // 8 MB
  float* h2 = (float*)(ws + 32 * MB);                     // 8 MB
  int* srcs = (int*)(ws + 40 * MB);                       // 1 MB
  float4* coo = (float4*)(ws + 41 * MB);                  // 256 KB + 64 KB pad
  int* sid = (int*)(ws + 41 * MB + 320 * KB);             // 64 KB
  int* sidx = (int*)(ws + 41 * MB + 384 * KB);            // 64 KB
  int* rank = (int*)(ws + 41 * MB + 448 * KB);            // 64 KB
  unsigned* hist = (unsigned*)(ws + 41 * MB + 512 * KB);  // 512 B
  unsigned* slabfill = (unsigned*)(ws + 41 * MB + 514 * KB);  // 512 B
  float* q3 = (float*)(ws + 42 * MB);                     // 768 KB
  float* out = (float*)d_out;

  hipMemsetAsync(hist, 0, NSLAB * sizeof(unsigned), stream);
  pack_all<<<NN / 256, 256, 0, stream>>>(x, coo, sid, hist);
  prefix_slabs<<<1, NSLAB, 0, stream>>>(hist, slabfill);
  rank_scatter<<<NN / 256, 256, 0, stream>>>(sid, slabfill, sidx, rank);
  knn_kernel<<<NN / (4 * QPW), 256, 0, stream>>>(coo, rank, srcs);
  gemm_qkvs<64><<<dim3(NN / 64, 8), 256, 0, stream>>>(
      x, Wq1, Wk1, Wv1, Ws1, bq1, bk1, bv1, bs1, rank, qs, kvh);
  attn_c128<<<NN / 8, 256, 0, stream>>>(qs, kvh, srcs, nullptr, h1, 0);
  gemm_qkvs<128><<<dim3(NN / 64, 8), 256, 0, stream>>>(
      h1, Wq2, Wk2, Wv2, Ws2, bq2, bk2, bv2, bs2, nullptr, qs, kvh);
  attn_c128<<<NN / 8, 256, 0, stream>>>(qs, kvh, srcs, h1, h2, 1);
  gemm_qkvs3<<<NN / 64, 256, 0, stream>>>(h2, Wq3, Wk3, Wv3, Ws3, bq3, bk3,
                                          bv3, bs3, q3);
  attn_c3<<<NN * 16 / 256, 256, 0, stream>>>(q3, srcs, sidx, out);
}

// Round 10
// 301.177 us; speedup vs baseline: 1.5280x; 1.1361x over previous
//
#include <hip/hip_runtime.h>
#include <math.h>

#define NN 16384
#define QPW 2     // queries per wave (r12: QPW=4 regressed; r13: 128-cand steps regressed)
#define CAP 128   // per-query LDS candidate buffer (u64 keys)
#define WM 64     // shrink watermark; shrink inside push keeps cnt <= 127
#define KTOP 17   // keep top-17 (incl. self at dist~0), drop self at output

typedef unsigned long long u64;

// ---------------- pack coords: x[:, :3] -> float4(x,y,z,-|p|^2/2) ------------
// r14: store -|p|^2/2 in .w so the knn hot loop is 3 FMA + 1 cmp:
// d <= th  <=>  L := q.p - |p|^2/2 >= cq  (d = |q|^2 - 2L, monotone).
__global__ __launch_bounds__(256) void pack_coords(const float* __restrict__ x,
                                                   float4* __restrict__ coo) {
  int i = blockIdx.x * 256 + threadIdx.x;
  float a = x[i * 64 + 0];
  float b = x[i * 64 + 1];
  float c = x[i * 64 + 2];
  coo[i] = make_float4(a, b, c, -0.5f * (a * a + b * b + c * c));
}

__device__ __forceinline__ int mbcnt64(u64 mask) {
  return __builtin_amdgcn_mbcnt_hi(
      (unsigned)(mask >> 32),
      __builtin_amdgcn_mbcnt_lo((unsigned)mask, 0));
}

// monotone float -> uint mapping (preserves total order incl. negatives)
__device__ __forceinline__ unsigned fmap(float d) {
  unsigned ub = __float_as_uint(d);
  return ub ^ ((unsigned)((int)ub >> 31) | 0x80000000u);
}

__device__ __forceinline__ float unfmap(unsigned ub) {
  unsigned fb = (ub & 0x80000000u) ? (ub ^ 0x80000000u) : ~ub;
  return __uint_as_float(fb);
}

// fp32 <-> bf16 (RNE, NaN-free data)
__device__ __forceinline__ unsigned short f2bf(float f) {
  unsigned u = __float_as_uint(f);
  return (unsigned short)((u + 0x7FFFu + ((u >> 16) & 1u)) >> 16);
}
__device__ __forceinline__ float bf2f(unsigned short h) {
  return __uint_as_float(((unsigned)h) << 16);
}

__device__ __forceinline__ u64 u64min(u64 a, u64 b) { return a < b ? a : b; }
__device__ __forceinline__ u64 u64max(u64 a, u64 b) { return a > b ? a : b; }

// full bitonic sort of 128 u64 keys held as 2 regs/lane, virtual index
// i0 = lane (r0), i1 = lane+64 (r1). Ascending. Used ONCE per query (final).
__device__ __forceinline__ void sort128(u64& r0, u64& r1, int lane) {
#pragma unroll
  for (int k = 2; k <= 128; k <<= 1) {
    if (k == 128) {  // jj = 64 stage: partner is the other reg, same lane
      u64 lo = u64min(r0, r1);
      r1 = u64max(r0, r1);
      r0 = lo;
    }
#pragma unroll
    for (int jj = (k == 128 ? 32 : (k >> 1)); jj >= 1; jj >>= 1) {
      const bool up = (lane & jj) == 0;
      const bool asc0 = (lane & k) == 0;
      const bool asc1 = ((lane | 64) & k) == 0;
      u64 o0 = __shfl_xor(r0, jj);
      u64 o1 = __shfl_xor(r1, jj);
      r0 = (up == asc0) ? u64min(r0, o0) : u64max(r0, o0);
      r1 = (up == asc1) ? u64min(r1, o1) : u64max(r1, o1);
    }
  }
}

// radix-select shrink: find p = KTOP-th smallest mapped key among
// buf[0..cnt), keep all entries with key <= p (ties kept -> exactness),
// compact to front. Key domain is fmap(-L), monotone in d for fixed query.
// Outputs cq = L_sel = -unfmap(p): keep candidates with L >= cq.
__device__ __forceinline__ void radix_shrink(u64* buf, int& cnt, float& cq,
                                             int lane) {
  const u64 k0 = (lane < cnt) ? buf[lane] : ~0ull;
  const u64 k1 = (lane + 64 < cnt) ? buf[lane + 64] : ~0ull;
  const unsigned d0 = (unsigned)(k0 >> 32);
  const unsigned d1 = (unsigned)(k1 >> 32);
  unsigned p = 0u;
#pragma unroll
  for (int b = 31; b >= 0; --b) {
    const unsigned c = p | (1u << b);
    const u64 b0 = __ballot(d0 < c);
    const u64 b1 = __ballot(d1 < c);
    const int n = __popcll(b0) + __popcll(b1);
    if (n < KTOP) p = c;  // invariant: count(key < p) < KTOP
  }
  const bool v0 = d0 <= p;
  const bool v1 = d1 <= p;
  const u64 m0 = __ballot(v0);
  const u64 m1 = __ballot(v1);
  const int base = __popcll(m0);
  if (v0) buf[mbcnt64(m0)] = k0;
  if (v1) buf[base + mbcnt64(m1)] = k1;
  cnt = base + __popcll(m1);
  cq = -unfmap(p);
}

// ---------------- kNN (r14 brute, r21 packaging): wave handles 2 nodes over
// the FULL database, 64 cand/step, hot test L >= cq (3 FMA + 1 cmp). r21:
// blocks of 128 (2 waves) instead of 256 (4 waves): same 8192 waves, but
// 4096 blocks -> 16 blocks/CU x 2 waves = 32 waves/CU (was 4 blocks/CU =
// 16 waves/CU, the measured 57% occupancy cap). No __syncthreads -> waves
// independent; only the bufs array shrinks to [2][QPW][CAP] = 4 KB.
// r15-r19 spatial-pruning variants all regressed (push/shrink serial chains
// dominate when candidates are pre-filtered); r20 permutation regressed
// (attn gathers were already L2-absorbed; scatter writes cost more). --------
__global__ __launch_bounds__(128) void knn_kernel(const float4* __restrict__ coo,
                                                  int* __restrict__ src) {
  __shared__ u64 bufs[2][QPW][CAP];  // 4 KB
  const int lane = threadIdx.x & 63;
  const int wid = threadIdx.x >> 6;
  const int node0 = blockIdx.x * (2 * QPW) + wid * QPW;

  float qx[QPW], qy[QPW], qz[QPW], cq[QPW];
  int cnt[QPW];
#pragma unroll
  for (int q = 0; q < QPW; ++q) {
    const float4 me = coo[node0 + q];
    qx[q] = me.x;
    qy[q] = me.y;
    qz[q] = me.z;
    cnt[q] = 0;
  }

  // pre-fill: candidates j = 0..127 direct into buffer, shrink
  {
    const float4 pa = coo[lane];
    const float4 pb = coo[64 + lane];
#pragma unroll
    for (int q = 0; q < QPW; ++q) {
      const float L0 = fmaf(qx[q], pa.x,
                        fmaf(qy[q], pa.y, fmaf(qz[q], pa.z, pa.w)));
      const float L1 = fmaf(qx[q], pb.x,
                        fmaf(qy[q], pb.y, fmaf(qz[q], pb.z, pb.w)));
      bufs[wid][q][lane] = ((u64)fmap(-L0) << 32) | (unsigned)lane;
      bufs[wid][q][64 + lane] = ((u64)fmap(-L1) << 32) | (unsigned)(64 + lane);
      cnt[q] = 128;
      radix_shrink(bufs[wid][q], cnt[q], cq[q], lane);
    }
  }

  // named prefetch slots: steps 2,3,4,5
  float4 s0 = coo[2 * 64 + lane];
  float4 s1 = coo[3 * 64 + lane];
  float4 s2 = coo[4 * 64 + lane];
  float4 s3 = coo[5 * 64 + lane];

  auto body = [&](const float4 cur, const int step) {
    const int j = step * 64 + lane;
    float L[QPW];
#pragma unroll
    for (int q = 0; q < QPW; ++q)
      L[q] = fmaf(qx[q], cur.x,
                  fmaf(qy[q], cur.y, fmaf(qz[q], cur.z, cur.w)));
    u64 mk[QPW];
#pragma unroll
    for (int q = 0; q < QPW; ++q) mk[q] = __ballot(L[q] >= cq[q]);
    if (mk[0] | mk[1]) {
#pragma unroll
      for (int q = 0; q < QPW; ++q) {
        if (mk[q]) {  // wave-uniform
          if (L[q] >= cq[q])
            bufs[wid][q][cnt[q] + mbcnt64(mk[q])] =
                ((u64)fmap(-L[q]) << 32) | (unsigned)j;
          cnt[q] += __popcll(mk[q]);
          if (cnt[q] >= WM) radix_shrink(bufs[wid][q], cnt[q], cq[q], lane);
        }
      }
    }
  };

  // steps 2..253 in 63 groups of 4; slots referenced by NAME only.
  // Over-reads at g=62 (steps 256,257) stay inside the pad after coo.
#pragma unroll 1
  for (int g = 0; g < 63; ++g) {
    const int base = 2 + g * 4;
    body(s0, base + 0);
    s0 = coo[(base + 4) * 64 + lane];
    body(s1, base + 1);
    s1 = coo[(base + 5) * 64 + lane];
    body(s2, base + 2);
    s2 = coo[(base + 6) * 64 + lane];
    body(s3, base + 3);
    s3 = coo[(base + 7) * 64 + lane];
  }
  body(s0, 254);
  body(s1, 255);

#pragma unroll 1
  for (int q = 0; q < QPW; ++q) {
    // final: exact (key, idx)-sorted top-17 via one bitonic sort
    u64 r0 = (lane < cnt[q]) ? bufs[wid][q][lane] : ~0ull;
    u64 r1 = (lane + 64 < cnt[q]) ? bufs[wid][q][lane + 64] : ~0ull;
    sort128(r0, r1, lane);
    const int idx = (int)(r0 & 0xFFFFFFFFull);
    const u64 selfm = __ballot((lane < KTOP) && (idx == node0 + q));
    const int s = selfm ? (__ffsll((long long)selfm) - 1) : 99;
    const int outrank = lane - (lane > s ? 1 : 0);
    if (lane < KTOP && lane != s && outrank < 16)
      src[(node0 + q) * 16 + outrank] = idx;
  }
}

// ---------------- fused q|k|v|s GEMM: [N,KD] x 4x[KD,128] ----------
// q,s -> fp32 qs[node][256] (q: 0..127, s: 128..255)
// k,v -> bf16 kvh[node][256] (k: 0..127, v: 128..255) -- halves attn gathers
template <int KD>
__global__ __launch_bounds__(256) void gemm_qkvs(
    const float* __restrict__ X, const float* __restrict__ W0,
    const float* __restrict__ W1, const float* __restrict__ W2,
    const float* __restrict__ W3, const float* __restrict__ B0,
    const float* __restrict__ B1, const float* __restrict__ B2,
    const float* __restrict__ B3, float* __restrict__ qs,
    unsigned short* __restrict__ kvh) {
  __shared__ float As[64][68];  // [k][row], padded k-stride 68
  __shared__ float Bs[64][64];  // [k][col]
  const int brow = blockIdx.x * 64;
  const int by = blockIdx.y;          // 0..7 -> (matrix, half)
  const int wi = by >> 1;
  const float* W = wi == 0 ? W0 : wi == 1 ? W1 : wi == 2 ? W2 : W3;
  const float* bias = wi == 0 ? B0 : wi == 1 ? B1 : wi == 2 ? B2 : B3;
  const int cbase = (by & 1) * 64;
  const int tx = threadIdx.x & 15;   // col group (4 cols)
  const int ty = threadIdx.x >> 4;   // row group (4 rows)

  float acc[4][4] = {};
  for (int k0 = 0; k0 < KD; k0 += 64) {
    __syncthreads();
#pragma unroll
    for (int i = 0; i < 4; ++i) {  // stage A transposed: 64 rows x 64 k
      const int flat = threadIdx.x * 4 + i * 1024;
      const int r = flat >> 6, kk = flat & 63;
      const float4 v = *(const float4*)&X[(brow + r) * KD + k0 + kk];
      As[kk + 0][r] = v.x;
      As[kk + 1][r] = v.y;
      As[kk + 2][r] = v.z;
      As[kk + 3][r] = v.w;
    }
#pragma unroll
    for (int i = 0; i < 4; ++i) {  // stage B: 64 k x 64 cols
      const int flat = threadIdx.x * 4 + i * 1024;
      const int kk = flat >> 6, c = flat & 63;
      *(float4*)&Bs[kk][c] = *(const float4*)&W[(k0 + kk) * 128 + cbase + c];
    }
    __syncthreads();
#pragma unroll 8
    for (int k = 0; k < 64; ++k) {
      const float4 a = *(const float4*)&As[k][ty * 4];
      const float4 b = *(const float4*)&Bs[k][tx * 4];
      const float av[4] = {a.x, a.y, a.z, a.w};
      const float bv[4] = {b.x, b.y, b.z, b.w};
#pragma unroll
      for (int i = 0; i < 4; ++i)
#pragma unroll
        for (int jj = 0; jj < 4; ++jj)
          acc[i][jj] = fmaf(av[i], bv[jj], acc[i][jj]);
    }
  }
  const float4 bi = *(const float4*)&bias[cbase + tx * 4];
  const int col = cbase + tx * 4;
#pragma unroll
  for (int i = 0; i < 4; ++i) {
    const int row = brow + ty * 4 + i;
    float4 o;
    o.x = acc[i][0] + bi.x;
    o.y = acc[i][1] + bi.y;
    o.z = acc[i][2] + bi.z;
    o.w = acc[i][3] + bi.w;
    if (wi == 0) {
      *(float4*)&qs[row * 256 + col] = o;
    } else if (wi == 3) {
      *(float4*)&qs[row * 256 + 128 + col] = o;
    } else {
      ushort4 h;
      h.x = f2bf(o.x);
      h.y = f2bf(o.y);
      h.z = f2bf(o.z);
      h.w = f2bf(o.w);
      *(ushort4*)&kvh[row * 256 + (wi == 1 ? col : 128 + col)] = h;
    }
  }
}

// ---------------- attention, c=128: 32-lane group per node ----
// q,s fp32 from qs; K,V gathered as bf16 ushort4 (half the bytes of fp32).
__global__ __launch_bounds__(256) void attn_c128(
    const float* __restrict__ qs, const unsigned short* __restrict__ kvh,
    const int* __restrict__ src, const float* __restrict__ res,
    float* __restrict__ hout, int do_res) {
  const int g = threadIdx.x >> 5;  // 8 groups of 32 lanes per block
  const int node = blockIdx.x * 8 + g;
  const int c = threadIdx.x & 31;
  const float4 q4 = ((const float4*)(qs + node * 256))[c];

  int nb[16];
#pragma unroll
  for (int r = 0; r < 16; ++r) nb[r] = src[node * 16 + r];

  float p[16];
#pragma unroll
  for (int r = 0; r < 16; ++r) {
    const ushort4 k4 = ((const ushort4*)(kvh + nb[r] * 256))[c];
    p[r] = q4.x * bf2f(k4.x) + q4.y * bf2f(k4.y) + q4.z * bf2f(k4.z) +
           q4.w * bf2f(k4.w);
  }
#pragma unroll
  for (int o = 16; o; o >>= 1) {  // group-local (xor offsets < 32)
#pragma unroll
    for (int r = 0; r < 16; ++r) p[r] += __shfl_xor(p[r], o);
  }

  float m = p[0];
#pragma unroll
  for (int r = 1; r < 16; ++r) m = fmaxf(m, p[r]);
  float w[16];
  float den = 0.0f;
#pragma unroll
  for (int r = 0; r < 16; ++r) {
    w[r] = __expf((p[r] - m) * 0.088388347648318447f);  // 1/sqrt(128)
    den += w[r];
  }
  const float inv = 1.0f / den;
  float o0 = 0.0f, o1 = 0.0f, o2 = 0.0f, o3 = 0.0f;
#pragma unroll
  for (int r = 0; r < 16; ++r) {
    const ushort4 v4 = ((const ushort4*)(kvh + nb[r] * 256 + 128))[c];
    const float ww = w[r] * inv;
    o0 = fmaf(ww, bf2f(v4.x), o0);
    o1 = fmaf(ww, bf2f(v4.y), o1);
    o2 = fmaf(ww, bf2f(v4.z), o2);
    o3 = fmaf(ww, bf2f(v4.w), o3);
  }
  const float4 s4 = ((const float4*)(qs + node * 256 + 128))[c];
  float r0 = o0 + s4.x, r1 = o1 + s4.y, r2 = o2 + s4.z, r3 = o3 + s4.w;
  if (do_res) {
    const float4 h4 = ((const float4*)(res + node * 128))[c];
    r0 += h4.x;
    r1 += h4.y;
    r2 += h4.z;
    r3 += h4.w;
  }
  ((float4*)(hout + node * 128))[c] =
      make_float4(tanhf(r0), tanhf(r1), tanhf(r2), tanhf(r3));
}

// ---------------- layer 3 GEMM: [N,128] x 4x[128,3] -> [N,12] ----------------
__global__ __launch_bounds__(256) void gemm_qkvs3(
    const float* __restrict__ H, const float* __restrict__ W0,
    const float* __restrict__ W1, const float* __restrict__ W2,
    const float* __restrict__ W3, const float* __restrict__ B0,
    const float* __restrict__ B1, const float* __restrict__ B2,
    const float* __restrict__ B3, float* __restrict__ out) {
  __shared__ float hs[64][132];
  __shared__ float wsh[128 * 12];
  __shared__ float bsh[12];
  const int brow = blockIdx.x * 64;
  if (threadIdx.x < 12) {
    const int mi = threadIdx.x / 3, c = threadIdx.x % 3;
    const float* Bsel = mi == 0 ? B0 : mi == 1 ? B1 : mi == 2 ? B2 : B3;
    bsh[threadIdx.x] = Bsel[c];
  }
  for (int t = threadIdx.x; t < 1536; t += 256) {
    const int k = t / 12, cc = t % 12;
    const int mi = cc / 3, c = cc % 3;
    const float* Wsel = mi == 0 ? W0 : mi == 1 ? W1 : mi == 2 ? W2 : W3;
    wsh[t] = Wsel[k * 3 + c];
  }
#pragma unroll
  for (int i = 0; i < 8; ++i) {
    const int flat = threadIdx.x * 4 + i * 1024;
    const int r = flat >> 7, kk = flat & 127;
    *(float4*)&hs[r][kk] = *(const float4*)&H[(brow + r) * 128 + kk];
  }
  __syncthreads();
  const int r = threadIdx.x >> 2;
  const int part = threadIdx.x & 3;
  float a0 = 0.0f, a1 = 0.0f, a2 = 0.0f;
#pragma unroll 4
  for (int k = 0; k < 128; ++k) {
    const float h = hs[r][k];
    a0 = fmaf(h, wsh[k * 12 + part * 3 + 0], a0);
    a1 = fmaf(h, wsh[k * 12 + part * 3 + 1], a1);
    a2 = fmaf(h, wsh[k * 12 + part * 3 + 2], a2);
  }
  const int row = brow + r;
  out[row * 12 + part * 3 + 0] = a0 + bsh[part * 3 + 0];
  out[row * 12 + part * 3 + 1] = a1 + bsh[part * 3 + 1];
  out[row * 12 + part * 3 + 2] = a2 + bsh[part * 3 + 2];
}

// ---------------- attention, c=3: 16 lanes per node ----------------
__global__ __launch_bounds__(256) void attn_c3(const float* __restrict__ q3,
                                               const int* __restrict__ src,
                                               float* __restrict__ out) {
  const int gid = blockIdx.x * 256 + threadIdx.x;
  const int node = gid >> 4, r = gid & 15;
  const int j = src[node * 16 + r];
  const float* qn = q3 + node * 12;
  const float* kj = q3 + j * 12 + 3;
  float alpha = (qn[0] * kj[0] + qn[1] * kj[1] + qn[2] * kj[2]) *
                0.57735026918962576f;  // 1/sqrt(3)
  float m = alpha;
#pragma unroll
  for (int o = 8; o; o >>= 1) m = fmaxf(m, __shfl_xor(m, o, 16));
  const float e = __expf(alpha - m);
  float den = e;
#pragma unroll
  for (int o = 8; o; o >>= 1) den += __shfl_xor(den, o, 16);
  const float wgt = e / den;
  const float* vj = q3 + j * 12 + 6;
  float o0 = wgt * vj[0], o1 = wgt * vj[1], o2 = wgt * vj[2];
#pragma unroll
  for (int o = 8; o; o >>= 1) {
    o0 += __shfl_xor(o0, o, 16);
    o1 += __shfl_xor(o1, o, 16);
    o2 += __shfl_xor(o2, o, 16);
  }
  if (r == 0) {
    const float* sn = q3 + node * 12 + 9;
    out[node * 3 + 0] = o0 + sn[0];
    out[node * 3 + 1] = o1 + sn[1];
    out[node * 3 + 2] = o2 + sn[2];
  }
}

extern "C" void kernel_launch(void* const* d_in, const int* in_sizes, int n_in,
                              void* d_out, int out_size, void* d_ws,
                              size_t ws_size, hipStream_t stream) {
  const float* x = (const float*)d_in[1];
  const float* Wq1 = (const float*)d_in[2];
  const float* bq1 = (const float*)d_in[3];
  const float* Wk1 = (const float*)d_in[4];
  const float* bk1 = (const float*)d_in[5];
  const float* Wv1 = (const float*)d_in[6];
  const float* bv1 = (const float*)d_in[7];
  const float* Ws1 = (const float*)d_in[8];
  const float* bs1 = (const float*)d_in[9];
  const float* Wq2 = (const float*)d_in[10];
  const float* bq2 = (const float*)d_in[11];
  const float* Wk2 = (const float*)d_in[12];
  const float* bk2 = (const float*)d_in[13];
  const float* Wv2 = (const float*)d_in[14];
  const float* bv2 = (const float*)d_in[15];
  const float* Ws2 = (const float*)d_in[16];
  const float* bs2 = (const float*)d_in[17];
  const float* Wq3 = (const float*)d_in[18];
  const float* bq3 = (const float*)d_in[19];
  const float* Wk3 = (const float*)d_in[20];
  const float* bk3 = (const float*)d_in[21];
  const float* Wv3 = (const float*)d_in[22];
  const float* bv3 = (const float*)d_in[23];
  const float* Ws3 = (const float*)d_in[24];
  const float* bs3 = (const float*)d_in[25];

  const size_t MB = 1024 * 1024;
  char* ws = (char*)d_ws;
  float* qs = (float*)(ws);                               // 16 MB (q|s fp32)
  unsigned short* kvh = (unsigned short*)(ws + 16 * MB);  // 8 MB (k|v bf16)
  float* h1 = (float*)(ws + 24 * MB);                     // 8 MB
  float* h2 = (float*)(ws + 32 * MB);                     // 8 MB
  int* src = (int*)(ws + 40 * MB);                        // 1 MB
  float4* coo = (float4*)(ws + 41 * MB);                  // 256 KB + 256 KB pad
  float* q3 = (float*)(ws + 42 * MB);                     // 768 KB
  float* out = (float*)d_out;

  pack_coords<<<NN / 256, 256, 0, stream>>>(x, coo);
  knn_kernel<<<NN / (2 * QPW), 128, 0, stream>>>(coo, src);
  gemm_qkvs<64><<<dim3(NN / 64, 8), 256, 0, stream>>>(
      x, Wq1, Wk1, Wv1, Ws1, bq1, bk1, bv1, bs1, qs, kvh);
  attn_c128<<<NN / 8, 256, 0, stream>>>(qs, kvh, src, nullptr, h1, 0);
  gemm_qkvs<128><<<dim3(NN / 64, 8), 256, 0, stream>>>(
      h1, Wq2, Wk2, Wv2, Ws2, bq2, bk2, bv2, bs2, qs, kvh);
  attn_c128<<<NN / 8, 256, 0, stream>>>(qs, kvh, src, h1, h2, 1);
  gemm_qkvs3<<<NN / 64, 256, 0, stream>>>(h2, Wq3, Wk3, Wv3, Ws3, bq3, bk3,
                                          bv3, bs3, q3);
  attn_c3<<<NN * 16 / 256, 256, 0, stream>>>(q3, src, out);
}